// Round 1
// 855.627 us; speedup vs baseline: 1.0808x; 1.0808x over previous
//
#include <hip/hip_runtime.h>

#define NN 50000
#define NE 800000
#define D 64

typedef float v4f __attribute__((ext_vector_type(4)));
typedef int v2i __attribute__((ext_vector_type(2)));

// Accumulate h[j] += (x[k]*scale) * W[k*64+j] for k=0..63.
// x is per-lane (divergent); W rows are uniform-address -> scalar loads.
// NT: nontemporal loads for stream-once inputs (edge_attr).
template <bool NT>
__device__ __forceinline__ void mlp_accum64(const float* __restrict__ x,
                                            const float* __restrict__ W,
                                            float scale, float* h) {
    const v4f* x4 = (const v4f*)x;
    #pragma unroll 1
    for (int k0 = 0; k0 < D; k0 += 8) {
        v4f v0, v1;
        if (NT) {
            v0 = __builtin_nontemporal_load(x4 + k0 / 4);
            v1 = __builtin_nontemporal_load(x4 + k0 / 4 + 1);
        } else {
            v0 = x4[k0 / 4];
            v1 = x4[k0 / 4 + 1];
        }
        float xa[8];
        xa[0] = v0[0]; xa[1] = v0[1]; xa[2] = v0[2]; xa[3] = v0[3];
        xa[4] = v1[0]; xa[5] = v1[1]; xa[6] = v1[2]; xa[7] = v1[3];
        #pragma unroll
        for (int kk = 0; kk < 8; ++kk) {
            const float xk = xa[kk] * scale;
            const float* Wr = W + (k0 + kk) * D;
            #pragma unroll
            for (int j = 0; j < D; ++j) h[j] = fmaf(xk, Wr[j], h[j]);
        }
    }
}

// k-outer layer2 for the node kernel (unchanged; occupancy irrelevant there).
// acc[j] = b2[j] + sum_k relu(h[k]) * W2[k*64+j]
__device__ __forceinline__ void mlp_layer2(const float* __restrict__ W2,
                                           const float* __restrict__ b2,
                                           const float* h, float* acc,
                                           float* myrow) {
    #pragma unroll
    for (int j = 0; j < D; ++j) acc[j] = b2[j];
    #pragma unroll
    for (int half = 0; half < 2; ++half) {
        #pragma unroll
        for (int k = 0; k < 32; ++k) myrow[k] = fmaxf(h[half * 32 + k], 0.f);
        #pragma unroll 1
        for (int k = 0; k < 32; ++k) {
            const float hk = myrow[k];
            const float* Wr = W2 + (half * 32 + k) * D;
            #pragma unroll
            for (int j = 0; j < D; ++j) acc[j] = fmaf(hk, Wr[j], acc[j]);
        }
    }
}

__global__ __launch_bounds__(256) void edge_kernel(
    const float* __restrict__ feats, const int* __restrict__ ei,
    const float* __restrict__ ea, const float* __restrict__ W1,
    const float* __restrict__ b1, const float* __restrict__ W2,
    const float* __restrict__ b2, float* __restrict__ e_out,
    float* __restrict__ agg, float* __restrict__ deg) {
    // LDS: transpose tile + dest-node buffer only (18432 B -> LDS allows
    // 8 blocks/CU; occupancy becomes VGPR-bound instead of LDS-bound).
    __shared__ float tbuf[4][64 * 17];  // 17408 B — wave-private transpose tile
    __shared__ int cbuf[4][64];         // 1024 B  — dest node per edge
    const int tid = threadIdx.x;
    const int w = tid >> 6;
    const int lane = tid & 63;
    const int eid = blockIdx.x * 256 + tid;       // grid*block == NE exactly
    const int ebase = blockIdx.x * 256 + w * 64;  // first edge of this wave

    const v2i rc = __builtin_nontemporal_load((const v2i*)ei + eid);
    const int r = rc[0];
    const int c = rc[1];
    cbuf[w][lane] = c;

    float h[D];
    #pragma unroll
    for (int j = 0; j < D; ++j) h[j] = b1[j];

    const float* xr = feats + (size_t)r * D;
    const float* xc = feats + (size_t)c * D;
    const float* xe = ea + (size_t)eid * D;

    // feats rows are re-gathered across edges -> cached loads.
    #pragma unroll 1
    for (int s = 0; s < 2; ++s)
        mlp_accum64<false>((s == 0) ? xr : xc, W1 + s * D * D, 1.0f, h);
    // edge_attr row is touched exactly once -> nontemporal (keep L2 for
    // feats gather + agg atomics).
    mlp_accum64<true>(xe, W1 + 2 * D * D, 1.0f, h);

    // ReLU in place; h[64] stays the only big live set through layer2.
    #pragma unroll
    for (int k = 0; k < D; ++k) h[k] = fmaxf(h[k], 0.f);

    // --- j-outer layer2 fused with transposed, line-coalesced emission ---
    // acc_j = b2[j] + sum_k h[k] * W2[k][j]; W2 column via uniform scalar
    // loads. No myrow LDS, no acc[64] register block -> no spills.
    float* T = tbuf[w];
    const int es = lane >> 4;  // edge subgroup 0..3
    const int js = lane & 15;  // column within 16-wide chunk
    #pragma unroll 1
    for (int c0 = 0; c0 < D; c0 += 16) {
        #pragma unroll 1
        for (int jj = 0; jj < 16; ++jj) {
            const int j = c0 + jj;
            const float* Wc = W2 + j;  // column j, stride D
            float p0 = b2[j], p1 = 0.f, p2 = 0.f, p3 = 0.f;
            #pragma unroll
            for (int k = 0; k < D; k += 4) {
                p0 = fmaf(h[k + 0], Wc[(k + 0) * D], p0);
                p1 = fmaf(h[k + 1], Wc[(k + 1) * D], p1);
                p2 = fmaf(h[k + 2], Wc[(k + 2) * D], p2);
                p3 = fmaf(h[k + 3], Wc[(k + 3) * D], p3);
            }
            T[lane * 17 + jj] = (p0 + p1) + (p2 + p3);
        }
        // Wave-synchronous LDS transpose; 4 full 64B lines per instruction.
        #pragma unroll 1
        for (int g = 0; g < 16; ++g) {
            const int o = g * 4 + es;        // edge slot in wave
            const float v = T[o * 17 + js];
            const int cd = cbuf[w][o];       // broadcast read
            __builtin_nontemporal_store(
                v, e_out + (size_t)(ebase + o) * D + c0 + js);
            unsafeAtomicAdd(agg + (size_t)cd * D + c0 + js, v);
        }
    }
    unsafeAtomicAdd(deg + c, 1.0f);
}

__global__ __launch_bounds__(64) void node_kernel(
    const float* __restrict__ feats, const float* __restrict__ agg,
    const float* __restrict__ deg, const float* __restrict__ W1,
    const float* __restrict__ b1, const float* __restrict__ W2,
    const float* __restrict__ b2, float* __restrict__ out) {
    __shared__ float sh[64 * 33];
    const int tid = threadIdx.x;
    const int n = blockIdx.x * 64 + tid;
    if (n >= NN) return;

    float h[D];
    #pragma unroll
    for (int j = 0; j < D; ++j) h[j] = b1[j];

    const float rd = 1.0f / fmaxf(deg[n], 1.0f);

    mlp_accum64<false>(feats + (size_t)n * D, W1, 1.0f, h);
    mlp_accum64<false>(agg + (size_t)n * D, W1 + D * D, rd, h);

    float acc[D];
    mlp_layer2(W2, b2, h, acc, sh + tid * 33);

    float4* o4 = (float4*)(out + (size_t)n * D);
    #pragma unroll
    for (int q = 0; q < 16; ++q)
        o4[q] = make_float4(acc[4 * q + 0], acc[4 * q + 1],
                            acc[4 * q + 2], acc[4 * q + 3]);
}

extern "C" void kernel_launch(void* const* d_in, const int* in_sizes, int n_in,
                              void* d_out, int out_size, void* d_ws,
                              size_t ws_size, hipStream_t stream) {
    const float* feats = (const float*)d_in[0];
    const int* ei      = (const int*)d_in[1];
    const float* ea    = (const float*)d_in[2];
    const float* W1e   = (const float*)d_in[3];
    const float* b1e   = (const float*)d_in[4];
    const float* W2e   = (const float*)d_in[5];
    const float* b2e   = (const float*)d_in[6];
    const float* W1n   = (const float*)d_in[7];
    const float* b1n   = (const float*)d_in[8];
    const float* W2n   = (const float*)d_in[9];
    const float* b2n   = (const float*)d_in[10];

    float* out_f = (float*)d_out;
    float* feats_out = out_f;                  // NN*D
    float* e_out = out_f + (size_t)NN * D;     // NE*D

    float* agg = (float*)d_ws;                 // NN*D
    float* deg = agg + (size_t)NN * D;         // NN

    hipMemsetAsync(d_ws, 0, ((size_t)NN * D + NN) * sizeof(float), stream);

    edge_kernel<<<NE / 256, 256, 0, stream>>>(feats, ei, ea, W1e, b1e, W2e,
                                              b2e, e_out, agg, deg);
    node_kernel<<<(NN + 63) / 64, 64, 0, stream>>>(feats, agg, deg, W1n, b1n,
                                                   W2n, b2n, feats_out);
}